// Round 2
// baseline (196.696 us; speedup 1.0000x reference)
//
#include <hip/hip_runtime.h>
#include <hip/hip_bf16.h>

#define NE 32
#define MM 256        // tokens per expert
#define DM 1024       // dmodel
#define ES 2048       // expert size

typedef __attribute__((ext_vector_type(8))) short short8;
typedef __attribute__((ext_vector_type(4))) float f32x4;
typedef unsigned int uint32;
typedef unsigned long long u64;
typedef unsigned short u16;

// One-instruction packed f32->bf16 (RNE). D[15:0]=bf16(a), D[31:16]=bf16(b).
__device__ __forceinline__ uint32 cvt_pk_bf16(float a, float b) {
    uint32 r;
    asm("v_cvt_pk_bf16_f32 %0, %1, %2" : "=v"(r) : "v"(a), "v"(b));
    return r;
}

__device__ __forceinline__ u64 pack4(float a, float b, float c, float d) {
    uint32 lo = cvt_pk_bf16(a, b);
    uint32 hi = cvt_pk_bf16(c, d);
    return (u64)lo | ((u64)hi << 32);
}

// Swizzled byte offsets into LDS tiles. Both tiles are [row][64 elems] with a
// 128B row; the 16B slot index is XOR-swizzled by row bits so that fragment
// ds_read_b128 (16 lanes reading 16 different rows at the same k-slot) spreads
// across all eight 16B slots (<=2-way, free per m136). Writes use the SAME
// mapping (pure permutation of LDS => correct by construction).
__device__ __forceinline__ int a_off(int m, int k) {
    return m * 128 + ((((k >> 3) ^ (m & 7)) & 7) << 4) + (((k >> 2) & 1) << 3);
}
__device__ __forceinline__ int b_off(int n, int k) {
    int X = ((n >> 2) & 7) ^ ((n & 3) << 1);
    return n * 128 + ((((k >> 3) ^ X) & 7) << 4) + (((k >> 2) & 1) << 3);
}

// Grouped GEMM: C[e] = act(A[e] @ B[e]) over NE experts.
// A: [NE*MM][K] (row-major, K contiguous), elem = float or bf16(u16)
// B: [NE][K][N] (row-major, N contiguous), fp32 -> converted to bf16 in staging
// C: [NE*MM][N], elem = float or bf16(u16)
template<int N, int K, bool RELU, typename AT, typename CT>
__global__ __launch_bounds__(256) void ec_gemm(
    const AT* __restrict__ A,
    const float* __restrict__ B,
    CT* __restrict__ C)
{
    constexpr int BM = 128, BN = 128, BK = 64;
    constexpr int MT = MM / BM;   // 2
    constexpr int NT = N / BN;

    int bid = blockIdx.x;
    int e   = bid / (MT * NT);
    int rem = bid % (MT * NT);
    int mt  = rem / NT;
    int nt  = rem % NT;

    const AT*    Ae = A + (size_t)(e * MM + mt * BM) * K;
    const float* Be = B + (size_t)e * K * N + (size_t)nt * BN;
    CT*          Ce = C + (size_t)(e * MM + mt * BM) * N + (size_t)nt * BN;

    __shared__ short As[BM * BK];   // 16 KiB, bf16, swizzled [m][k]
    __shared__ short Bs[BN * BK];   // 16 KiB, bf16, swizzled transposed [n][k]
    char* AsB = (char*)As;
    char* BsB = (char*)Bs;

    const int t    = threadIdx.x;
    const int lane = t & 63;
    const int w    = t >> 6;          // wave 0..3
    const int wm   = (w >> 1) * 64;   // wave tile: 64x64
    const int wn   = (w & 1) * 64;
    const int lr   = lane & 15;
    const int lg   = lane >> 4;

    // staging assignments
    const int ak4 = (t & 15) * 4;     // A: k quad within BK
    const int am0 = t >> 4;           // A: base row (0..15), rows m0+16i
    const int bn4 = (t & 31) * 4;     // B: n quad within BN
    const int bkb = (t >> 5) * 4;     // B: k quad base (0..28), plus +32 group

    f32x4 acc[4][4] = {};

    for (int kt = 0; kt < K; kt += BK) {
        // ---------- stage A (convert f32->bf16 if needed) ----------
        if constexpr (sizeof(AT) == 4) {
            #pragma unroll
            for (int i = 0; i < 8; ++i) {
                int m = am0 + i * 16;
                float4 v = *(const float4*)((const float*)Ae + (size_t)m * K + kt + ak4);
                *(u64*)(AsB + a_off(m, ak4)) = pack4(v.x, v.y, v.z, v.w);
            }
        } else {
            #pragma unroll
            for (int i = 0; i < 8; ++i) {
                int m = am0 + i * 16;
                u64 v = *(const u64*)((const u16*)Ae + (size_t)m * K + kt + ak4);
                *(u64*)(AsB + a_off(m, ak4)) = v;
            }
        }
        // ---------- stage B: 4x4 register transpose + convert ----------
        #pragma unroll
        for (int g = 0; g < 2; ++g) {
            int k4 = g * 32 + bkb;
            const float* Bk = Be + (size_t)(kt + k4) * N + bn4;
            float4 r0 = *(const float4*)(Bk);
            float4 r1 = *(const float4*)(Bk + N);
            float4 r2 = *(const float4*)(Bk + 2 * (size_t)N);
            float4 r3 = *(const float4*)(Bk + 3 * (size_t)N);
            *(u64*)(BsB + b_off(bn4 + 0, k4)) = pack4(r0.x, r1.x, r2.x, r3.x);
            *(u64*)(BsB + b_off(bn4 + 1, k4)) = pack4(r0.y, r1.y, r2.y, r3.y);
            *(u64*)(BsB + b_off(bn4 + 2, k4)) = pack4(r0.z, r1.z, r2.z, r3.z);
            *(u64*)(BsB + b_off(bn4 + 3, k4)) = pack4(r0.w, r1.w, r2.w, r3.w);
        }
        __syncthreads();
        // ---------- compute ----------
        #pragma unroll
        for (int kk = 0; kk < 2; ++kk) {
            int k = kk * 32 + lg * 8;   // 8-aligned -> 16B-aligned slot
            short8 af[4], bfr[4];
            #pragma unroll
            for (int i = 0; i < 4; ++i)
                af[i] = *(const short8*)(AsB + a_off(wm + i * 16 + lr, k));
            #pragma unroll
            for (int j = 0; j < 4; ++j)
                bfr[j] = *(const short8*)(BsB + b_off(wn + j * 16 + lr, k));
            #pragma unroll
            for (int i = 0; i < 4; ++i)
                #pragma unroll
                for (int j = 0; j < 4; ++j)
                    acc[i][j] = __builtin_amdgcn_mfma_f32_16x16x32_bf16(af[i], bfr[j], acc[i][j], 0, 0, 0);
        }
        __syncthreads();
    }

    // ---------- epilogue: C/D layout col=lane&15, row=(lane>>4)*4+reg ----------
    #pragma unroll
    for (int i = 0; i < 4; ++i) {
        #pragma unroll
        for (int rr = 0; rr < 4; ++rr) {
            int row = wm + i * 16 + lg * 4 + rr;
            CT* Cp = Ce + (size_t)row * N + wn + lr;
            if constexpr (sizeof(CT) == 2) {
                // convert in pairs (j, j+1) with one cvt_pk each
                #pragma unroll
                for (int jp = 0; jp < 2; ++jp) {
                    float v0 = acc[i][2 * jp + 0][rr];
                    float v1 = acc[i][2 * jp + 1][rr];
                    if constexpr (RELU) {
                        v0 = v0 > 0.0f ? v0 : 0.0f;
                        v1 = v1 > 0.0f ? v1 : 0.0f;
                    }
                    uint32 p = cvt_pk_bf16(v0, v1);
                    ((u16*)Cp)[(2 * jp + 0) * 16] = (u16)(p & 0xffffu);
                    ((u16*)Cp)[(2 * jp + 1) * 16] = (u16)(p >> 16);
                }
            } else {
                #pragma unroll
                for (int j = 0; j < 4; ++j) {
                    float v = acc[i][j][rr];
                    if constexpr (RELU) v = v > 0.0f ? v : 0.0f;
                    ((float*)Cp)[j * 16] = v;
                }
            }
        }
    }
}

extern "C" void kernel_launch(void* const* d_in, const int* in_sizes, int n_in,
                              void* d_out, int out_size, void* d_ws, size_t ws_size,
                              hipStream_t stream) {
    const float* x    = (const float*)d_in[0];
    // d_in[1] = gate: dead code in the reference output -- unused.
    const float* lin1 = (const float*)d_in[2];
    const float* lin2 = (const float*)d_in[3];
    float* out = (float*)d_out;
    u16* h = (u16*)d_ws;   // [NE][MM][ES] bf16 = 33.5 MB (relu already applied)

    dim3 blk(256);
    // GEMM1: h = relu(x @ W1), per expert 256x2048, K=1024
    ec_gemm<ES, DM, true,  float, u16 ><<<NE * (MM/128) * (ES/128), blk, 0, stream>>>(x, lin1, h);
    // GEMM2: out = h @ W2, per expert 256x1024, K=2048
    ec_gemm<DM, ES, false, u16,  float><<<NE * (MM/128) * (DM/128), blk, 0, stream>>>(h, lin2, out);
}

// Round 3
// 185.224 us; speedup vs baseline: 1.0619x; 1.0619x over previous
//
#include <hip/hip_runtime.h>
#include <hip/hip_bf16.h>

#define NE 32
#define MM 256        // tokens per expert
#define DM 1024       // dmodel
#define ES 2048       // expert size

typedef __attribute__((ext_vector_type(8))) short short8;
typedef __attribute__((ext_vector_type(4))) float f32x4;
typedef unsigned int uint32;
typedef unsigned long long u64;
typedef unsigned short u16;

// One-instruction packed f32->bf16 (RNE). D[15:0]=bf16(a), D[31:16]=bf16(b).
__device__ __forceinline__ uint32 cvt_pk_bf16(float a, float b) {
    uint32 r;
    asm("v_cvt_pk_bf16_f32 %0, %1, %2" : "=v"(r) : "v"(a), "v"(b));
    return r;
}
__device__ __forceinline__ u64 pack4(float a, float b, float c, float d) {
    return (u64)cvt_pk_bf16(a, b) | ((u64)cvt_pk_bf16(c, d) << 32);
}

// Async global->LDS, 16B per lane. LDS dest is wave-uniform base + lane*16.
__device__ __forceinline__ void gl_lds16(const void* g, void* l) {
    __builtin_amdgcn_global_load_lds(
        (const __attribute__((address_space(1))) uint32*)g,
        (__attribute__((address_space(3))) uint32*)l, 16, 0, 0);
}

// B LDS tile: bf16 [n][k], 128B rows, 16B-slot XOR swizzle (verified r1/r2).
__device__ __forceinline__ int b_off(int n, int k) {
    int X = ((n >> 2) & 7) ^ ((n & 3) << 1);
    return n * 128 + ((((k >> 3) ^ X) & 7) << 4) + (((k >> 2) & 1) << 3);
}

// Grouped GEMM: C[e] = act(A[e] @ B[e]) over NE experts.
// A: [NE*MM][K], f32 or bf16, staged via global_load_lds with source-side
//    granule swizzle s' = s ^ (m&7) so fragment ds_read_b128 is conflict-free.
// B: [NE][K][N] f32, prefetched to regs one K-step ahead, cvt+transposed to LDS.
template<int N, int K, bool RELU, typename AT, typename CT>
__global__ __launch_bounds__(256) void ec_gemm(
    const AT* __restrict__ A,
    const float* __restrict__ B,
    CT* __restrict__ C)
{
    constexpr int BM = 128, BN = 128, BK = 64;
    constexpr int MT = MM / BM;   // 2
    constexpr int NT = N / BN;
    constexpr int NSTEP = K / BK;
    constexpr bool AF32 = (sizeof(AT) == 4);

    int bid = blockIdx.x;
    int e   = bid / (MT * NT);
    int rem = bid % (MT * NT);
    int mt  = rem / NT;
    int nt  = rem % NT;

    const AT*    Ae = A + (size_t)(e * MM + mt * BM) * K;
    const float* Be = B + (size_t)e * K * N + (size_t)nt * BN;
    CT*          Ce = C + (size_t)(e * MM + mt * BM) * N + (size_t)nt * BN;

    __shared__ char AsB[BM * BK * sizeof(AT)];   // f32: 32KB, bf16: 16KB
    __shared__ short Bs[BN * BK];                // 16KB bf16 [n][k] swizzled
    char* BsB = (char*)Bs;

    const int t    = threadIdx.x;
    const int lane = t & 63;
    const int w    = t >> 6;
    const int wm   = (w >> 1) * 64;
    const int wn   = (w & 1) * 64;
    const int lr   = lane & 15;
    const int lg   = lane >> 4;

    // B staging thread mapping (unchanged from verified r1)
    const int bn4 = (t & 31) * 4;     // n quad
    const int bkb = (t >> 5) * 4;     // k quad base; +32 for group 1

    f32x4  acc[4][4] = {};
    float4 br[2][4];                  // prefetched B: 2 k-groups x 4 rows

    // ---- A stage: async global->LDS, source pre-swizzled ----
    auto gloadA = [&](int kt) {
        if constexpr (AF32) {
            // 8 insts/wave; each: 1KB = 4 rows x 16 granules (16B = 4 f32)
            #pragma unroll
            for (int r = 0; r < 8; ++r) {
                int reg = w * 8 + r;
                int m   = reg * 4 + (lane >> 4);
                int s   = (lane & 15) ^ (m & 7);
                const float* g = (const float*)Ae + (size_t)m * K + kt + s * 4;
                gl_lds16(g, AsB + reg * 1024);
            }
        } else {
            // 4 insts/wave; each: 1KB = 8 rows x 8 granules (16B = 8 bf16)
            #pragma unroll
            for (int r = 0; r < 4; ++r) {
                int reg = w * 4 + r;
                int m   = reg * 8 + (lane >> 3);
                int s   = (lane & 7) ^ (m & 7);
                const u16* g = (const u16*)Ae + (size_t)m * K + kt + s * 8;
                gl_lds16(g, AsB + reg * 1024);
            }
        }
    };

    // ---- B stage: prefetch to regs / convert+write later ----
    auto loadB = [&](int kt) {
        #pragma unroll
        for (int g = 0; g < 2; ++g) {
            int k4 = g * 32 + bkb;
            const float* Bk = Be + (size_t)(kt + k4) * N + bn4;
            br[g][0] = *(const float4*)(Bk);
            br[g][1] = *(const float4*)(Bk + N);
            br[g][2] = *(const float4*)(Bk + 2 * (size_t)N);
            br[g][3] = *(const float4*)(Bk + 3 * (size_t)N);
        }
    };
    auto writeB = [&]() {
        #pragma unroll
        for (int g = 0; g < 2; ++g) {
            int k4 = g * 32 + bkb;
            *(u64*)(BsB + b_off(bn4 + 0, k4)) = pack4(br[g][0].x, br[g][1].x, br[g][2].x, br[g][3].x);
            *(u64*)(BsB + b_off(bn4 + 1, k4)) = pack4(br[g][0].y, br[g][1].y, br[g][2].y, br[g][3].y);
            *(u64*)(BsB + b_off(bn4 + 2, k4)) = pack4(br[g][0].z, br[g][1].z, br[g][2].z, br[g][3].z);
            *(u64*)(BsB + b_off(bn4 + 3, k4)) = pack4(br[g][0].w, br[g][1].w, br[g][2].w, br[g][3].w);
        }
    };

    // ---- A fragment read (with f32->bf16 cvt for GEMM1) ----
    auto readA = [&](int i, int k) -> short8 {
        int m = wm + i * 16 + lr;
        if constexpr (AF32) {
            int s0 = (k >> 2) ^ (m & 7);
            int s1 = ((k + 4) >> 2) ^ (m & 7);
            f32x4 lo = *(const f32x4*)(AsB + m * 256 + s0 * 16);
            f32x4 hi = *(const f32x4*)(AsB + m * 256 + s1 * 16);
            union { short8 s; uint32 u[4]; } fr;
            fr.u[0] = cvt_pk_bf16(lo[0], lo[1]);
            fr.u[1] = cvt_pk_bf16(lo[2], lo[3]);
            fr.u[2] = cvt_pk_bf16(hi[0], hi[1]);
            fr.u[3] = cvt_pk_bf16(hi[2], hi[3]);
            return fr.s;
        } else {
            int s = ((k >> 3) ^ (m & 7)) & 7;
            return *(const short8*)(AsB + m * 128 + s * 16);
        }
    };

    // ---- prologue: stage tile 0 ----
    loadB(0);
    gloadA(0);
    writeB();
    __syncthreads();   // drains vmcnt (gloadA) + lgkm (writeB)

    for (int ks = 0; ks < NSTEP; ++ks) {
        const bool pf = (ks + 1 < NSTEP);
        if (pf) loadB((ks + 1) * BK);   // in flight across the MFMA phase

        #pragma unroll
        for (int kk = 0; kk < 2; ++kk) {
            int k = kk * 32 + lg * 8;
            short8 af[4], bfr[4];
            #pragma unroll
            for (int i = 0; i < 4; ++i) af[i] = readA(i, k);
            #pragma unroll
            for (int j = 0; j < 4; ++j)
                bfr[j] = *(const short8*)(BsB + b_off(wn + j * 16 + lr, k));
            #pragma unroll
            for (int i = 0; i < 4; ++i)
                #pragma unroll
                for (int j = 0; j < 4; ++j)
                    acc[i][j] = __builtin_amdgcn_mfma_f32_16x16x32_bf16(af[i], bfr[j], acc[i][j], 0, 0, 0);
        }
        __syncthreads();   // all waves done reading LDS tile ks

        if (pf) {
            gloadA((ks + 1) * BK);
            writeB();
            __syncthreads();   // tile ks+1 fully in LDS (barrier drains vmcnt+lgkm)
        }
    }

    // ---- epilogue: C/D layout col=lane&15, row=(lane>>4)*4+reg (verified) ----
    #pragma unroll
    for (int i = 0; i < 4; ++i) {
        #pragma unroll
        for (int rr = 0; rr < 4; ++rr) {
            int row = wm + i * 16 + lg * 4 + rr;
            CT* Cp = Ce + (size_t)row * N + wn + lr;
            if constexpr (sizeof(CT) == 2) {
                #pragma unroll
                for (int jp = 0; jp < 2; ++jp) {
                    float v0 = acc[i][2 * jp + 0][rr];
                    float v1 = acc[i][2 * jp + 1][rr];
                    if constexpr (RELU) {
                        v0 = v0 > 0.0f ? v0 : 0.0f;
                        v1 = v1 > 0.0f ? v1 : 0.0f;
                    }
                    uint32 p = cvt_pk_bf16(v0, v1);
                    ((u16*)Cp)[(2 * jp + 0) * 16] = (u16)(p & 0xffffu);
                    ((u16*)Cp)[(2 * jp + 1) * 16] = (u16)(p >> 16);
                }
            } else {
                #pragma unroll
                for (int j = 0; j < 4; ++j) {
                    float v = acc[i][j][rr];
                    if constexpr (RELU) v = v > 0.0f ? v : 0.0f;
                    ((float*)Cp)[j * 16] = v;
                }
            }
        }
    }
}

extern "C" void kernel_launch(void* const* d_in, const int* in_sizes, int n_in,
                              void* d_out, int out_size, void* d_ws, size_t ws_size,
                              hipStream_t stream) {
    const float* x    = (const float*)d_in[0];
    // d_in[1] = gate: dead code in the reference output -- unused.
    const float* lin1 = (const float*)d_in[2];
    const float* lin2 = (const float*)d_in[3];
    float* out = (float*)d_out;
    u16* h = (u16*)d_ws;   // [NE][MM][ES] bf16 = 33.5 MB (relu applied)

    dim3 blk(256);
    // GEMM1: h = relu(x @ W1), per expert 256x2048, K=1024
    ec_gemm<ES, DM, true,  float, u16 ><<<NE * (MM/128) * (ES/128), blk, 0, stream>>>(x, lin1, h);
    // GEMM2: out = h @ W2, per expert 256x1024, K=2048
    ec_gemm<DM, ES, false, u16,  float><<<NE * (MM/128) * (DM/128), blk, 0, stream>>>(h, lin2, out);
}